// Round 8
// baseline (1565.024 us; speedup 1.0000x reference)
//
#include <hip/hip_runtime.h>

#define N_NODES 100000
#define M_EDGES 500000
#define D 128
#define SLOPE 0.01f
#define EPS 1e-5f

typedef __attribute__((ext_vector_type(8))) short bf16x8;
typedef __attribute__((ext_vector_type(4))) float f32x4;
typedef __attribute__((ext_vector_type(4))) unsigned int u32x4;

__device__ __forceinline__ unsigned short f2bf(float f) {
    union { float f; unsigned u; } v; v.f = f;
    unsigned r = v.u + 0x7FFF + ((v.u >> 16) & 1);   // RNE
    return (unsigned short)(r >> 16);
}
__device__ __forceinline__ float bf2f(unsigned short u) {
    union { unsigned u; float f; } v; v.u = ((unsigned)u) << 16; return v.f;
}
__device__ __forceinline__ u32x4 pack8v(f32x4 a, f32x4 b) {
    u32x4 r;
    r.x = ((unsigned)f2bf(a.y) << 16) | f2bf(a.x);
    r.y = ((unsigned)f2bf(a.w) << 16) | f2bf(a.z);
    r.z = ((unsigned)f2bf(b.y) << 16) | f2bf(b.x);
    r.w = ((unsigned)f2bf(b.w) << 16) | f2bf(b.z);
    return r;
}

// ---------------------------------------------------------------------------
// Weight pre-convert: fp32 [L][K][128] -> bf16 fragment-major [L][K/32][8][64][8]
// ---------------------------------------------------------------------------
__global__ void wconv_kernel(const float* __restrict__ src, unsigned short* __restrict__ dst,
                             int K, int total)
{
    int i = blockIdx.x * 256 + threadIdx.x;
    if (i >= total) return;
    int layer_sz = K * 128;
    int l = i / layer_sz;
    int r = i - l * layer_sz;
    int j    = r & 7;
    int lane = (r >> 3) & 63;
    int nt   = (r >> 9) & 7;
    int kk   = r >> 12;
    int row  = kk * 32 + ((lane >> 4) << 3) + j;
    int col  = nt * 16 + (lane & 15);
    dst[i] = f2bf(src[(size_t)l * layer_sz + row * 128 + col]);
}

__global__ void h2b_kernel(const float* __restrict__ src, unsigned short* __restrict__ dst, int total8)
{
    int i = blockIdx.x * 256 + threadIdx.x;
    if (i >= total8) return;
    f32x4 a = ((const f32x4*)src)[2 * i];
    f32x4 b = ((const f32x4*)src)[2 * i + 1];
    ((u32x4*)dst)[i] = pack8v(a, b);
}

// ---------------------------------------------------------------------------
// CSR build: counts -> exclusive scan -> slot fill
// ---------------------------------------------------------------------------
__global__ void count_kernel(const int* __restrict__ ht, int* __restrict__ cnt, int m)
{
    int e = blockIdx.x * 256 + threadIdx.x;
    if (e < m) {
        atomicAdd(&cnt[ht[2 * e]],     1);
        atomicAdd(&cnt[ht[2 * e + 1]], 1);
    }
}

__global__ void scanA_kernel(const int* __restrict__ cnt, int* __restrict__ partial,
                             int* __restrict__ bsum, int n)
{
    __shared__ int tmp[256];
    int t = threadIdx.x, i = blockIdx.x * 256 + t;
    int v = (i < n) ? cnt[i] : 0;
    tmp[t] = v;
    __syncthreads();
    for (int s = 1; s < 256; s <<= 1) {
        int x = (t >= s) ? tmp[t - s] : 0;
        __syncthreads();
        tmp[t] += x;
        __syncthreads();
    }
    if (i < n) partial[i] = tmp[t] - v;
    if (t == 255) bsum[blockIdx.x] = tmp[255];
}

__global__ void scanB_kernel(int* __restrict__ bsum, int nb)
{
    __shared__ int tmp[512];
    int t = threadIdx.x;
    int v = (t < nb) ? bsum[t] : 0;
    tmp[t] = v;
    __syncthreads();
    for (int s = 1; s < 512; s <<= 1) {
        int x = (t >= s) ? tmp[t - s] : 0;
        __syncthreads();
        tmp[t] += x;
        __syncthreads();
    }
    if (t < nb) bsum[t] = tmp[t] - v;
}

__global__ void scanC_kernel(const int* __restrict__ partial, const int* __restrict__ bsum,
                             int* __restrict__ off, int* __restrict__ pos, int n)
{
    int i = blockIdx.x * 256 + threadIdx.x;
    if (i < n) {
        int o = partial[i] + bsum[blockIdx.x];
        off[i] = o;
        pos[i] = o;
    }
    if (i == 0) off[n] = 2 * M_EDGES;
}

__global__ void fill_kernel(const int* __restrict__ ht, int* __restrict__ pos,
                            int* __restrict__ slotF, int* __restrict__ slotB, int m)
{
    int e = blockIdx.x * 256 + threadIdx.x;
    if (e < m) {
        int2 p = ((const int2*)ht)[e];
        slotF[e] = atomicAdd(&pos[p.y], 1);
        slotB[e] = atomicAdd(&pos[p.x], 1);
    }
}

// ---------------------------------------------------------------------------
// Fused edge kernel: 2 waves/block, 64 edges/block, each wave owns HALF of N
// (nt 0..3 -> cols wv*64 .. wv*64+63). acc = 64 AGPR/wave -> 3 waves/SIMD.
// Shared en tile; LN via cross-wave LDS partials; 3 block barriers total.
// ---------------------------------------------------------------------------
template <bool E_F32, bool WRITE_E>
__global__ __launch_bounds__(128, 3)
void edge_mfma_kernel(const unsigned short* __restrict__ Hb,
                      const float* __restrict__ E0,
                      const unsigned short* __restrict__ Ebf,
                      unsigned short* __restrict__ Eout,
                      const int* __restrict__ ht,
                      const unsigned short* __restrict__ Weu,
                      const unsigned short* __restrict__ Wf,
                      const unsigned short* __restrict__ Wb,
                      const float* __restrict__ beu,
                      const float* __restrict__ lneg, const float* __restrict__ lneb,
                      const float* __restrict__ bfw, const float* __restrict__ bbw,
                      const int* __restrict__ slotF, const int* __restrict__ slotB,
                      unsigned short* __restrict__ msg)
{
    __shared__ unsigned char en[16384];     // 64 E/en rows, bf16, XOR-swizzled
    __shared__ float2 part[2][64];          // per-wave LN partials (s, ss)

    const int tid = threadIdx.x;
    const int wv  = tid >> 6;               // wave: which N-half
    const int ln  = tid & 63;
    const int g   = ln >> 4;
    const int c15 = ln & 15;
    const int ew0 = blockIdx.x * 64;
    const int ntb = wv * 4;                 // global nt base for this wave

    int eL = ew0 + ln; if (eL >= M_EDGES) eL = M_EDGES - 1;
    const int slotFv = slotF[eL];
    const int slotBv = slotB[eL];

    // ---- stage 64 E rows into LDS (both waves cooperate) ----
#pragma unroll
    for (int it = 0; it < 8; ++it) {
        int lin = it * 2048 + tid * 16;
        int row = lin >> 8;
        int e   = ew0 + row;
        int es  = (e < M_EDGES) ? e : (M_EDGES - 1);
        int elem = (lin & 255) >> 1;
        u32x4 pk;
        if (E_F32) {
            const float* s = E0 + (size_t)es * D + elem;
            pk = pack8v(*(const f32x4*)s, *(const f32x4*)(s + 4));
        } else {
            pk = *(const u32x4*)(Ebf + (size_t)es * D + elem);
        }
        *(u32x4*)(en + (lin ^ ((row & 7) << 4))) = pk;
    }

    // ---- per-lane A-row pointers ----
    const unsigned short* hrow[4];
    const unsigned short* trow[4];
#pragma unroll
    for (int m = 0; m < 4; ++m) {
        int e = ew0 + m * 16 + c15;
        int es = (e < M_EDGES) ? e : (M_EDGES - 1);
        int2 p = ((const int2*)ht)[es];
        hrow[m] = Hb + (size_t)p.x * D;
        trow[m] = Hb + (size_t)p.y * D;
    }
    const int swz = (c15 & 7) << 4;

    __syncthreads();    // en staged

    f32x4 acc[4][4];

    // =========================== GEMM1: triple(384) @ Weu ===================
#pragma unroll
    for (int m = 0; m < 4; ++m)
#pragma unroll
        for (int nt = 0; nt < 4; ++nt) acc[m][nt] = (f32x4){0.f, 0.f, 0.f, 0.f};

    {
        const u32x4* Wg = (const u32x4*)Weu;
        u32x4 bc[4];
        bf16x8 a[4], an[4];
        auto loadA = [&](int kk, int m) -> bf16x8 {
            if (kk < 4)
                return *(const bf16x8*)(hrow[m] + kk * 32 + g * 8);
            if (kk < 8)
                return *(const bf16x8*)(en + (((m * 16 + c15) * 256 + (kk - 4) * 64 + g * 16) ^ swz));
            return *(const bf16x8*)(trow[m] + (kk - 8) * 32 + g * 8);
        };
#pragma unroll
        for (int nt = 0; nt < 4; ++nt) bc[nt] = Wg[(ntb + nt) * 64 + ln];
#pragma unroll
        for (int m = 0; m < 4; ++m) a[m] = loadA(0, m);
#pragma unroll
        for (int kk = 0; kk < 12; ++kk) {
            if (kk < 11) {
#pragma unroll
                for (int m = 0; m < 4; ++m) an[m] = loadA(kk + 1, m);
            }
#pragma unroll
            for (int nt = 0; nt < 4; ++nt) {
                bf16x8 b = *(const bf16x8*)&bc[nt];
#pragma unroll
                for (int m = 0; m < 4; ++m)
                    acc[m][nt] = __builtin_amdgcn_mfma_f32_16x16x32_bf16(a[m], b, acc[m][nt], 0, 0, 0);
                if (kk < 11) bc[nt] = Wg[(kk + 1) * 512 + (ntb + nt) * 64 + ln];
            }
#pragma unroll
            for (int m = 0; m < 4; ++m) a[m] = an[m];
        }
    }

    // ====== bias + leaky + residual; cross-wave LN partials; write en =======
    {
        float be[4], lg4[4], lb4[4];
#pragma unroll
        for (int nt = 0; nt < 4; ++nt) {
            int idx = (ntb + nt) * 16 + c15;
            be[nt]  = beu[idx];
            lg4[nt] = lneg[idx];
            lb4[nt] = lneb[idx];
        }
        // step 1: own-half partials
#pragma unroll
        for (int m = 0; m < 4; ++m) {
            float s[4] = {0.f,0.f,0.f,0.f}, ss[4] = {0.f,0.f,0.f,0.f};
#pragma unroll
            for (int nt = 0; nt < 4; ++nt) {
#pragma unroll
                for (int r = 0; r < 4; ++r) {
                    int row = m * 16 + g * 4 + r;
                    float x = acc[m][nt][r] + be[nt];
                    x = (x >= 0.f) ? x : SLOPE * x;
                    int lin = row * 256 + ((ntb + nt) * 16 + c15) * 2;
                    x += bf2f(*(const unsigned short*)(en + (lin ^ ((row & 7) << 4))));
                    acc[m][nt][r] = x;
                    s[r] += x; ss[r] += x * x;
                }
            }
#pragma unroll
            for (int d = 1; d < 16; d <<= 1) {
#pragma unroll
                for (int r = 0; r < 4; ++r) {
                    s[r]  += __shfl_xor(s[r],  d);
                    ss[r] += __shfl_xor(ss[r], d);
                }
            }
            if (c15 == 0) {
#pragma unroll
                for (int r = 0; r < 4; ++r)
                    part[wv][m * 16 + g * 4 + r] = make_float2(s[r], ss[r]);
            }
        }
        __syncthreads();    // partials visible
        // step 2: combine, normalize, write own-half en
#pragma unroll
        for (int m = 0; m < 4; ++m) {
            float mu[4], rs[4];
#pragma unroll
            for (int r = 0; r < 4; ++r) {
                int row = m * 16 + g * 4 + r;
                float2 po = part[wv ^ 1][row];
                float2 ps = part[wv][row];
                float sm  = ps.x + po.x;
                float sq  = ps.y + po.y;
                mu[r] = sm * (1.0f / 128.0f);
                float var = sq * (1.0f / 128.0f) - mu[r] * mu[r];
                rs[r] = rsqrtf(var + EPS);
            }
#pragma unroll
            for (int nt = 0; nt < 4; ++nt) {
#pragma unroll
                for (int r = 0; r < 4; ++r) {
                    int row = m * 16 + g * 4 + r;
                    float xn = (acc[m][nt][r] - mu[r]) * rs[r] * lg4[nt] + lb4[nt];
                    int lin = row * 256 + ((ntb + nt) * 16 + c15) * 2;
                    *(unsigned short*)(en + (lin ^ ((row & 7) << 4))) = f2bf(xn);
                }
            }
        }
    }
    __syncthreads();    // en normalized, full rows visible

    // ---- write E_new to global (layer 0 only): own half cols ----
    if (WRITE_E) {
#pragma unroll
        for (int it = 0; it < 8; ++it) {
            int idx = it * 64 + ln;
            int row = idx >> 3;
            int sub = idx & 7;
            int e   = ew0 + row;
            if (e < M_EDGES) {
                int lin = row * 256 + wv * 128 + sub * 16;
                *(u32x4*)(Eout + (size_t)e * D + wv * 64 + sub * 8) =
                    *(const u32x4*)(en + (lin ^ ((row & 7) << 4)));
            }
        }
    }

    // =================== GEMM2 ([head|en] @ Wf) + GEMM3 ([tail|en] @ Wb) ====
#pragma unroll
    for (int pass = 0; pass < 2; ++pass) {
        const u32x4* Wg = (const u32x4*)(pass == 0 ? Wf : Wb);
#pragma unroll
        for (int m = 0; m < 4; ++m)
#pragma unroll
            for (int nt = 0; nt < 4; ++nt) acc[m][nt] = (f32x4){0.f, 0.f, 0.f, 0.f};

        {
            u32x4 bc[4];
            bf16x8 a[4], an[4];
            auto loadA = [&](int kk, int m) -> bf16x8 {
                if (kk < 4)
                    return *(const bf16x8*)((pass == 0 ? hrow[m] : trow[m]) + kk * 32 + g * 8);
                return *(const bf16x8*)(en + (((m * 16 + c15) * 256 + (kk - 4) * 64 + g * 16) ^ swz));
            };
#pragma unroll
            for (int nt = 0; nt < 4; ++nt) bc[nt] = Wg[(ntb + nt) * 64 + ln];
#pragma unroll
            for (int m = 0; m < 4; ++m) a[m] = loadA(0, m);
#pragma unroll
            for (int kk = 0; kk < 8; ++kk) {
                if (kk < 7) {
#pragma unroll
                    for (int m = 0; m < 4; ++m) an[m] = loadA(kk + 1, m);
                }
#pragma unroll
                for (int nt = 0; nt < 4; ++nt) {
                    bf16x8 b = *(const bf16x8*)&bc[nt];
#pragma unroll
                    for (int m = 0; m < 4; ++m)
                        acc[m][nt] = __builtin_amdgcn_mfma_f32_16x16x32_bf16(a[m], b, acc[m][nt], 0, 0, 0);
                    if (kk < 7) bc[nt] = Wg[(kk + 1) * 512 + (ntb + nt) * 64 + ln];
                }
#pragma unroll
                for (int m = 0; m < 4; ++m) a[m] = an[m];
            }
        }

        // ---- scatter: plain packed-bf16 stores into CSR slots, own half ----
        {
            const float* bias = pass == 0 ? bfw : bbw;
            const int slotv = pass == 0 ? slotFv : slotBv;
            float bv[4];
#pragma unroll
            for (int nt = 0; nt < 4; ++nt) bv[nt] = bias[(ntb + nt) * 16 + c15];
#pragma unroll
            for (int m = 0; m < 4; ++m) {
#pragma unroll
                for (int r = 0; r < 4; ++r) {
                    int erow = m * 16 + g * 4 + r;
                    bool val = (ew0 + erow < M_EDGES);
                    int slot = __shfl(slotv, erow);
                    unsigned* base = (unsigned*)(msg + (size_t)slot * D + wv * 64 + (c15 & ~1));
#pragma unroll
                    for (int nt = 0; nt < 4; ++nt) {
                        float v = acc[m][nt][r] + bv[nt];
                        float o = __shfl_xor(v, 1);
                        float lo = (ln & 1) ? o : v;
                        float hi = (ln & 1) ? v : o;
                        unsigned pk = ((unsigned)f2bf(hi) << 16) | f2bf(lo);
                        if (val && ((ln & 1) == (nt >> 1)))
                            base[nt * 8] = pk;
                    }
                }
            }
        }
    }
}

// ---------------------------------------------------------------------------
// node_kernel: gather CSR slot range, mean, leaky, +H, LN. f32 accumulate.
// ---------------------------------------------------------------------------
__global__ __launch_bounds__(256)
void node_kernel(const float* __restrict__ Hin, const unsigned short* __restrict__ msg,
                 const int* __restrict__ off, const float* __restrict__ g,
                 const float* __restrict__ b, float* __restrict__ Hout,
                 unsigned short* __restrict__ Hb, int n)
{
    const int wave = threadIdx.x >> 6, lane = threadIdx.x & 63;
    const int node = blockIdx.x * 4 + wave;
    if (node >= n) return;

    const int beg = off[node], end = off[node + 1];
    const float inv = 1.0f / fmaxf((float)(end - beg), 1.0f);
    const unsigned* mb = (const unsigned*)msg;

    float a0 = 0.f, a1 = 0.f;
    int i = beg;
    for (; i + 1 < end; i += 2) {
        unsigned v0 = mb[(size_t)i * 64 + lane];
        unsigned v1 = mb[(size_t)(i + 1) * 64 + lane];
        a0 += bf2f((unsigned short)(v0 & 0xffff)) + bf2f((unsigned short)(v1 & 0xffff));
        a1 += bf2f((unsigned short)(v0 >> 16))    + bf2f((unsigned short)(v1 >> 16));
    }
    if (i < end) {
        unsigned v0 = mb[(size_t)i * 64 + lane];
        a0 += bf2f((unsigned short)(v0 & 0xffff));
        a1 += bf2f((unsigned short)(v0 >> 16));
    }

    a0 *= inv; a1 *= inv;
    a0 = (a0 >= 0.f) ? a0 : SLOPE * a0;
    a1 = (a1 >= 0.f) ? a1 : SLOPE * a1;

    size_t base = (size_t)node * D + 2 * lane;
    float x0 = a0 + Hin[base];
    float x1 = a1 + Hin[base + 1];

    float s = x0 + x1, ss = x0 * x0 + x1 * x1;
#pragma unroll
    for (int d = 1; d < 64; d <<= 1) {
        s  += __shfl_xor(s, d);
        ss += __shfl_xor(ss, d);
    }
    float mu  = s * (1.0f / 128.0f);
    float var = ss * (1.0f / 128.0f) - mu * mu;
    float rs  = rsqrtf(var + EPS);

    float o0 = (x0 - mu) * rs * g[2 * lane]     + b[2 * lane];
    float o1 = (x1 - mu) * rs * g[2 * lane + 1] + b[2 * lane + 1];
    Hout[base]     = o0;
    Hout[base + 1] = o1;
    Hb[base]       = f2bf(o0);
    Hb[base + 1]   = f2bf(o1);
}

// ---------------------------------------------------------------------------
extern "C" void kernel_launch(void* const* d_in, const int* in_sizes, int n_in,
                              void* d_out, int out_size, void* d_ws, size_t ws_size,
                              hipStream_t stream)
{
    const float* H0   = (const float*)d_in[0];
    const float* E0   = (const float*)d_in[1];
    const int*   ht   = (const int*)d_in[2];
    const float* Weu  = (const float*)d_in[4];
    const float* beu  = (const float*)d_in[5];
    const float* lneg = (const float*)d_in[6];
    const float* lneb = (const float*)d_in[7];
    const float* Wf   = (const float*)d_in[8];
    const float* bfw  = (const float*)d_in[9];
    const float* Wb   = (const float*)d_in[10];
    const float* bbw  = (const float*)d_in[11];
    const float* lnhg = (const float*)d_in[12];
    const float* lnhb = (const float*)d_in[13];

    float* Hout = (float*)d_out;

    // workspace layout (bytes)
    char* ws = (char*)d_ws;
    unsigned short* msg    = (unsigned short*)(ws);                  // 256,000,000
    unsigned short* Ebuf   = (unsigned short*)(ws + 256000000);      // 128,000,000
    unsigned short* Hb     = (unsigned short*)(ws + 384000000);      //  25,600,000
    unsigned short* Weu_sw = (unsigned short*)(ws + 409600000);      //     196,608
    unsigned short* Wf_sw  = (unsigned short*)(ws + 409796608);      //     131,072
    unsigned short* Wb_sw  = (unsigned short*)(ws + 409927680);      //     131,072
    int*            cnt    = (int*)(ws + 410058752);                 //     400,000
    int*            partial= (int*)(ws + 410458752);                 //     400,000
    int*            bsum   = (int*)(ws + 410858752);                 //       2,048
    int*            off    = (int*)(ws + 410860800);                 //     400,016
    int*            pos    = (int*)(ws + 411260816);                 //     400,000
    int*            slotF  = (int*)(ws + 411660816);                 //   2,000,000
    int*            slotB  = (int*)(ws + 413660816);                 //   2,000,000

    wconv_kernel<<<(2*384*128 + 255)/256, 256, 0, stream>>>(Weu, Weu_sw, 384, 2*384*128);
    wconv_kernel<<<(2*256*128 + 255)/256, 256, 0, stream>>>(Wf,  Wf_sw,  256, 2*256*128);
    wconv_kernel<<<(2*256*128 + 255)/256, 256, 0, stream>>>(Wb,  Wb_sw,  256, 2*256*128);
    h2b_kernel<<<(N_NODES * D / 8 + 255)/256, 256, 0, stream>>>(H0, Hb, N_NODES * D / 8);

    // ---- CSR build ----
    const int nscan = (N_NODES + 255) / 256;   // 391
    hipMemsetAsync(cnt, 0, (size_t)N_NODES * sizeof(int), stream);
    count_kernel<<<(M_EDGES + 255) / 256, 256, 0, stream>>>(ht, cnt, M_EDGES);
    scanA_kernel<<<nscan, 256, 0, stream>>>(cnt, partial, bsum, N_NODES);
    scanB_kernel<<<1, 512, 0, stream>>>(bsum, nscan);
    scanC_kernel<<<nscan, 256, 0, stream>>>(partial, bsum, off, pos, N_NODES);
    fill_kernel<<<(M_EDGES + 255) / 256, 256, 0, stream>>>(ht, pos, slotF, slotB, M_EDGES);

    const int eblocks = (M_EDGES + 63) / 64;   // 7813

    for (int l = 0; l < 2; ++l) {
        const float* Hin = (l == 0) ? H0 : Hout;

        if (l == 0) {
            edge_mfma_kernel<true, true><<<eblocks, 128, 0, stream>>>(
                Hb, E0, nullptr, Ebuf, ht,
                Weu_sw, Wf_sw, Wb_sw,
                beu, lneg, lneb, bfw, bbw, slotF, slotB, msg);
        } else {
            edge_mfma_kernel<false, false><<<eblocks, 128, 0, stream>>>(
                Hb, nullptr, Ebuf, nullptr, ht,
                Weu_sw + 49152, Wf_sw + 32768, Wb_sw + 32768,
                beu + D, lneg + D, lneb + D, bfw + D, bbw + D, slotF, slotB, msg);
        }

        node_kernel<<<(N_NODES + 3) / 4, 256, 0, stream>>>(
            Hin, msg, off, lnhg + (size_t)l * D, lnhb + (size_t)l * D, Hout, Hb, N_NODES);
    }
}

// Round 9
// 848.793 us; speedup vs baseline: 1.8438x; 1.8438x over previous
//
#include <hip/hip_runtime.h>

#define N_NODES 100000
#define M_EDGES 500000
#define D 128
#define SLOPE 0.01f
#define EPS 1e-5f

typedef __attribute__((ext_vector_type(8))) short bf16x8;
typedef __attribute__((ext_vector_type(4))) float f32x4;
typedef __attribute__((ext_vector_type(4))) unsigned int u32x4;

__device__ __forceinline__ unsigned short f2bf(float f) {
    union { float f; unsigned u; } v; v.f = f;
    unsigned r = v.u + 0x7FFF + ((v.u >> 16) & 1);   // RNE
    return (unsigned short)(r >> 16);
}
__device__ __forceinline__ float bf2f(unsigned short u) {
    union { unsigned u; float f; } v; v.u = ((unsigned)u) << 16; return v.f;
}
__device__ __forceinline__ u32x4 pack8v(f32x4 a, f32x4 b) {
    u32x4 r;
    r.x = ((unsigned)f2bf(a.y) << 16) | f2bf(a.x);
    r.y = ((unsigned)f2bf(a.w) << 16) | f2bf(a.z);
    r.z = ((unsigned)f2bf(b.y) << 16) | f2bf(b.x);
    r.w = ((unsigned)f2bf(b.w) << 16) | f2bf(b.z);
    return r;
}

// ---------------------------------------------------------------------------
// Weight pre-convert: fp32 [L][K][128] -> bf16 fragment-major [L][K/32][8][64][8]
// ---------------------------------------------------------------------------
__global__ void wconv_kernel(const float* __restrict__ src, unsigned short* __restrict__ dst,
                             int K, int total)
{
    int i = blockIdx.x * 256 + threadIdx.x;
    if (i >= total) return;
    int layer_sz = K * 128;
    int l = i / layer_sz;
    int r = i - l * layer_sz;
    int j    = r & 7;
    int lane = (r >> 3) & 63;
    int nt   = (r >> 9) & 7;
    int kk   = r >> 12;
    int row  = kk * 32 + ((lane >> 4) << 3) + j;
    int col  = nt * 16 + (lane & 15);
    dst[i] = f2bf(src[(size_t)l * layer_sz + row * 128 + col]);
}

__global__ void h2b_kernel(const float* __restrict__ src, unsigned short* __restrict__ dst, int total8)
{
    int i = blockIdx.x * 256 + threadIdx.x;
    if (i >= total8) return;
    f32x4 a = ((const f32x4*)src)[2 * i];
    f32x4 b = ((const f32x4*)src)[2 * i + 1];
    ((u32x4*)dst)[i] = pack8v(a, b);
}

// ---------------------------------------------------------------------------
// CSR build: counts -> exclusive scan -> slot fill
// ---------------------------------------------------------------------------
__global__ void count_kernel(const int* __restrict__ ht, int* __restrict__ cnt, int m)
{
    int e = blockIdx.x * 256 + threadIdx.x;
    if (e < m) {
        atomicAdd(&cnt[ht[2 * e]],     1);
        atomicAdd(&cnt[ht[2 * e + 1]], 1);
    }
}

__global__ void scanA_kernel(const int* __restrict__ cnt, int* __restrict__ partial,
                             int* __restrict__ bsum, int n)
{
    __shared__ int tmp[256];
    int t = threadIdx.x, i = blockIdx.x * 256 + t;
    int v = (i < n) ? cnt[i] : 0;
    tmp[t] = v;
    __syncthreads();
    for (int s = 1; s < 256; s <<= 1) {
        int x = (t >= s) ? tmp[t - s] : 0;
        __syncthreads();
        tmp[t] += x;
        __syncthreads();
    }
    if (i < n) partial[i] = tmp[t] - v;
    if (t == 255) bsum[blockIdx.x] = tmp[255];
}

__global__ void scanB_kernel(int* __restrict__ bsum, int nb)
{
    __shared__ int tmp[512];
    int t = threadIdx.x;
    int v = (t < nb) ? bsum[t] : 0;
    tmp[t] = v;
    __syncthreads();
    for (int s = 1; s < 512; s <<= 1) {
        int x = (t >= s) ? tmp[t - s] : 0;
        __syncthreads();
        tmp[t] += x;
        __syncthreads();
    }
    if (t < nb) bsum[t] = tmp[t] - v;
}

__global__ void scanC_kernel(const int* __restrict__ partial, const int* __restrict__ bsum,
                             int* __restrict__ off, int* __restrict__ pos, int n)
{
    int i = blockIdx.x * 256 + threadIdx.x;
    if (i < n) {
        int o = partial[i] + bsum[blockIdx.x];
        off[i] = o;
        pos[i] = o;
    }
    if (i == 0) off[n] = 2 * M_EDGES;
}

__global__ void fill_kernel(const int* __restrict__ ht, int* __restrict__ pos,
                            int* __restrict__ slotF, int* __restrict__ slotB, int m)
{
    int e = blockIdx.x * 256 + threadIdx.x;
    if (e < m) {
        int2 p = ((const int2*)ht)[e];
        slotF[e] = atomicAdd(&pos[p.y], 1);
        slotB[e] = atomicAdd(&pos[p.x], 1);
    }
}

// ---------------------------------------------------------------------------
// Barrier-free fused edge kernel (r7 dataflow), ROLLED k-loops to fit I$.
// ONE wave per block, 64 edges (4 M-tiles). CSR slot stores, no atomics.
// ---------------------------------------------------------------------------
template <bool E_F32, bool WRITE_E>
__global__ __launch_bounds__(64, 2)
void edge_mfma_kernel(const unsigned short* __restrict__ Hb,
                      const float* __restrict__ E0,
                      const unsigned short* __restrict__ Ebf,
                      unsigned short* __restrict__ Eout,
                      const int* __restrict__ ht,
                      const unsigned short* __restrict__ Weu,
                      const unsigned short* __restrict__ Wf,
                      const unsigned short* __restrict__ Wb,
                      const float* __restrict__ beu,
                      const float* __restrict__ lneg, const float* __restrict__ lneb,
                      const float* __restrict__ bfw, const float* __restrict__ bbw,
                      const int* __restrict__ slotF, const int* __restrict__ slotB,
                      unsigned short* __restrict__ msg)
{
    __shared__ unsigned char en[16384];     // 64 E/en rows, bf16, XOR-swizzled

    const int ln  = threadIdx.x;
    const int g   = ln >> 4;
    const int c15 = ln & 15;
    const int ew0 = blockIdx.x * 64;

    int eL = ew0 + ln; if (eL >= M_EDGES) eL = M_EDGES - 1;
    const int slotFv = slotF[eL];
    const int slotBv = slotB[eL];

    // ---- stage 64 E rows into LDS (bf16, XOR-swizzled) ----
#pragma unroll
    for (int it = 0; it < 16; ++it) {
        int lin = it * 1024 + ln * 16;
        int row = lin >> 8;
        int e   = ew0 + row;
        int es  = (e < M_EDGES) ? e : (M_EDGES - 1);
        int elem = (lin & 255) >> 1;
        u32x4 pk;
        if (E_F32) {
            const float* s = E0 + (size_t)es * D + elem;
            pk = pack8v(*(const f32x4*)s, *(const f32x4*)(s + 4));
        } else {
            pk = *(const u32x4*)(Ebf + (size_t)es * D + elem);
        }
        *(u32x4*)(en + (lin ^ ((row & 7) << 4))) = pk;
    }

    // ---- per-lane A-row pointers (lane's rows: c15 + 16*m, m=0..3) ----
    const unsigned short* hrow[4];
    const unsigned short* trow[4];
    int ebase[4];
#pragma unroll
    for (int m = 0; m < 4; ++m) {
        int e = ew0 + m * 16 + c15;
        int es = (e < M_EDGES) ? e : (M_EDGES - 1);
        int2 p = ((const int2*)ht)[es];
        hrow[m] = Hb + (size_t)p.x * D;
        trow[m] = Hb + (size_t)p.y * D;
        ebase[m] = (m * 16 + c15) * 256 + g * 16;
    }
    const int swz = (c15 & 7) << 4;

    f32x4 acc[4][8];

    // =========================== GEMM1: triple(384) @ Weu ===================
#pragma unroll
    for (int m = 0; m < 4; ++m)
#pragma unroll
        for (int nt = 0; nt < 8; ++nt) acc[m][nt] = (f32x4){0.f, 0.f, 0.f, 0.f};

    {
        const u32x4* Wg = (const u32x4*)Weu;
        u32x4 bc[8];
        bf16x8 a[4], an[4];
#pragma unroll
        for (int nt = 0; nt < 8; ++nt) bc[nt] = Wg[nt * 64 + ln];
#pragma unroll
        for (int m = 0; m < 4; ++m) a[m] = *(const bf16x8*)(hrow[m] + g * 8);
#pragma unroll 1
        for (int kk = 0; kk < 12; ++kk) {
            if (kk < 11) {
                int kn = kk + 1;
#pragma unroll
                for (int m = 0; m < 4; ++m) {
                    bf16x8 v;
                    if (kn < 4)      v = *(const bf16x8*)(hrow[m] + kn * 32 + g * 8);
                    else if (kn < 8) v = *(const bf16x8*)(en + ((ebase[m] + (kn - 4) * 64) ^ swz));
                    else             v = *(const bf16x8*)(trow[m] + (kn - 8) * 32 + g * 8);
                    an[m] = v;
                }
            }
#pragma unroll
            for (int nt = 0; nt < 8; ++nt) {
                bf16x8 b = *(const bf16x8*)&bc[nt];
#pragma unroll
                for (int m = 0; m < 4; ++m)
                    acc[m][nt] = __builtin_amdgcn_mfma_f32_16x16x32_bf16(a[m], b, acc[m][nt], 0, 0, 0);
                if (kk < 11) bc[nt] = Wg[(kk + 1) * 512 + nt * 64 + ln];
            }
#pragma unroll
            for (int m = 0; m < 4; ++m) a[m] = an[m];
        }
    }

    // ============ bias + leaky + residual + LayerNorm -> en (LDS) ===========
    {
        float be[8], lg[8], lb[8];
#pragma unroll
        for (int nt = 0; nt < 8; ++nt) {
            be[nt] = beu[nt * 16 + c15];
            lg[nt] = lneg[nt * 16 + c15];
            lb[nt] = lneb[nt * 16 + c15];
        }
#pragma unroll
        for (int m = 0; m < 4; ++m) {
            float s[4] = {0.f,0.f,0.f,0.f}, ss[4] = {0.f,0.f,0.f,0.f};
#pragma unroll
            for (int nt = 0; nt < 8; ++nt) {
#pragma unroll
                for (int r = 0; r < 4; ++r) {
                    int row = m * 16 + g * 4 + r;
                    float x = acc[m][nt][r] + be[nt];
                    x = (x >= 0.f) ? x : SLOPE * x;
                    int lin = row * 256 + (nt * 16 + c15) * 2;
                    x += bf2f(*(const unsigned short*)(en + (lin ^ ((row & 7) << 4))));
                    acc[m][nt][r] = x;
                    s[r] += x; ss[r] += x * x;
                }
            }
#pragma unroll
            for (int d = 1; d < 16; d <<= 1) {
#pragma unroll
                for (int r = 0; r < 4; ++r) {
                    s[r]  += __shfl_xor(s[r],  d);
                    ss[r] += __shfl_xor(ss[r], d);
                }
            }
            float mu[4], rs[4];
#pragma unroll
            for (int r = 0; r < 4; ++r) {
                mu[r] = s[r] * (1.0f / 128.0f);
                float var = ss[r] * (1.0f / 128.0f) - mu[r] * mu[r];
                rs[r] = rsqrtf(var + EPS);
            }
#pragma unroll
            for (int nt = 0; nt < 8; ++nt) {
#pragma unroll
                for (int r = 0; r < 4; ++r) {
                    int row = m * 16 + g * 4 + r;
                    float xn = (acc[m][nt][r] - mu[r]) * rs[r] * lg[nt] + lb[nt];
                    int lin = row * 256 + (nt * 16 + c15) * 2;
                    *(unsigned short*)(en + (lin ^ ((row & 7) << 4))) = f2bf(xn);
                }
            }
        }
    }

    // ---- write E_new to global (layer 0 only) ----
    if (WRITE_E) {
#pragma unroll
        for (int it = 0; it < 16; ++it) {
            int lin = it * 1024 + ln * 16;
            int row = lin >> 8;
            int e   = ew0 + row;
            if (e < M_EDGES)
                *(u32x4*)(Eout + (size_t)e * D + ((lin & 255) >> 1)) =
                    *(const u32x4*)(en + (lin ^ ((row & 7) << 4)));
        }
    }

    // =================== GEMM2 ([head|en] @ Wf) + GEMM3 ([tail|en] @ Wb) ====
#pragma unroll 1
    for (int pass = 0; pass < 2; ++pass) {
        const u32x4* Wg = (const u32x4*)(pass == 0 ? Wf : Wb);
        const unsigned short* ar[4];
#pragma unroll
        for (int m = 0; m < 4; ++m) ar[m] = (pass == 0) ? hrow[m] : trow[m];
#pragma unroll
        for (int m = 0; m < 4; ++m)
#pragma unroll
            for (int nt = 0; nt < 8; ++nt) acc[m][nt] = (f32x4){0.f, 0.f, 0.f, 0.f};

        {
            u32x4 bc[8];
            bf16x8 a[4], an[4];
#pragma unroll
            for (int nt = 0; nt < 8; ++nt) bc[nt] = Wg[nt * 64 + ln];
#pragma unroll
            for (int m = 0; m < 4; ++m) a[m] = *(const bf16x8*)(ar[m] + g * 8);
#pragma unroll 1
            for (int kk = 0; kk < 8; ++kk) {
                if (kk < 7) {
                    int kn = kk + 1;
#pragma unroll
                    for (int m = 0; m < 4; ++m) {
                        bf16x8 v;
                        if (kn < 4) v = *(const bf16x8*)(ar[m] + kn * 32 + g * 8);
                        else        v = *(const bf16x8*)(en + ((ebase[m] + (kn - 4) * 64) ^ swz));
                        an[m] = v;
                    }
                }
#pragma unroll
                for (int nt = 0; nt < 8; ++nt) {
                    bf16x8 b = *(const bf16x8*)&bc[nt];
#pragma unroll
                    for (int m = 0; m < 4; ++m)
                        acc[m][nt] = __builtin_amdgcn_mfma_f32_16x16x32_bf16(a[m], b, acc[m][nt], 0, 0, 0);
                    if (kk < 7) bc[nt] = Wg[(kk + 1) * 512 + nt * 64 + ln];
                }
#pragma unroll
                for (int m = 0; m < 4; ++m) a[m] = an[m];
            }
        }

        // ---- scatter: plain packed-bf16 stores into CSR slots (NO atomics) --
        {
            const float* bias = (pass == 0) ? bfw : bbw;
            const int slotv = (pass == 0) ? slotFv : slotBv;
            float bv[8];
#pragma unroll
            for (int nt = 0; nt < 8; ++nt) bv[nt] = bias[nt * 16 + c15];
#pragma unroll
            for (int m = 0; m < 4; ++m) {
#pragma unroll
                for (int r = 0; r < 4; ++r) {
                    int erow = m * 16 + g * 4 + r;
                    bool val = (ew0 + erow < M_EDGES);
                    int slot = __shfl(slotv, erow);
                    unsigned* base = (unsigned*)(msg + (size_t)slot * D + (c15 & ~1));
#pragma unroll
                    for (int nt = 0; nt < 8; ++nt) {
                        float v = acc[m][nt][r] + bv[nt];
                        float o = __shfl_xor(v, 1);
                        float lo = (ln & 1) ? o : v;
                        float hi = (ln & 1) ? v : o;
                        unsigned pk = ((unsigned)f2bf(hi) << 16) | f2bf(lo);
                        if (val && ((ln & 1) == (nt >> 2)))
                            base[nt * 8] = pk;
                    }
                }
            }
        }
    }
}

// ---------------------------------------------------------------------------
// node_kernel: gather CSR slot range, mean, leaky, +H, LN. f32 accumulate.
// ---------------------------------------------------------------------------
__global__ __launch_bounds__(256)
void node_kernel(const float* __restrict__ Hin, const unsigned short* __restrict__ msg,
                 const int* __restrict__ off, const float* __restrict__ g,
                 const float* __restrict__ b, float* __restrict__ Hout,
                 unsigned short* __restrict__ Hb, int n)
{
    const int wave = threadIdx.x >> 6, lane = threadIdx.x & 63;
    const int node = blockIdx.x * 4 + wave;
    if (node >= n) return;

    const int beg = off[node], end = off[node + 1];
    const float inv = 1.0f / fmaxf((float)(end - beg), 1.0f);
    const unsigned* mb = (const unsigned*)msg;

    float a0 = 0.f, a1 = 0.f;
    int i = beg;
    for (; i + 1 < end; i += 2) {
        unsigned v0 = mb[(size_t)i * 64 + lane];
        unsigned v1 = mb[(size_t)(i + 1) * 64 + lane];
        a0 += bf2f((unsigned short)(v0 & 0xffff)) + bf2f((unsigned short)(v1 & 0xffff));
        a1 += bf2f((unsigned short)(v0 >> 16))    + bf2f((unsigned short)(v1 >> 16));
    }
    if (i < end) {
        unsigned v0 = mb[(size_t)i * 64 + lane];
        a0 += bf2f((unsigned short)(v0 & 0xffff));
        a1 += bf2f((unsigned short)(v0 >> 16));
    }

    a0 *= inv; a1 *= inv;
    a0 = (a0 >= 0.f) ? a0 : SLOPE * a0;
    a1 = (a1 >= 0.f) ? a1 : SLOPE * a1;

    size_t base = (size_t)node * D + 2 * lane;
    float x0 = a0 + Hin[base];
    float x1 = a1 + Hin[base + 1];

    float s = x0 + x1, ss = x0 * x0 + x1 * x1;
#pragma unroll
    for (int d = 1; d < 64; d <<= 1) {
        s  += __shfl_xor(s, d);
        ss += __shfl_xor(ss, d);
    }
    float mu  = s * (1.0f / 128.0f);
    float var = ss * (1.0f / 128.0f) - mu * mu;
    float rs  = rsqrtf(var + EPS);

    float o0 = (x0 - mu) * rs * g[2 * lane]     + b[2 * lane];
    float o1 = (x1 - mu) * rs * g[2 * lane + 1] + b[2 * lane + 1];
    Hout[base]     = o0;
    Hout[base + 1] = o1;
    Hb[base]       = f2bf(o0);
    Hb[base + 1]   = f2bf(o1);
}

// ---------------------------------------------------------------------------
extern "C" void kernel_launch(void* const* d_in, const int* in_sizes, int n_in,
                              void* d_out, int out_size, void* d_ws, size_t ws_size,
                              hipStream_t stream)
{
    const float* H0   = (const float*)d_in[0];
    const float* E0   = (const float*)d_in[1];
    const int*   ht   = (const int*)d_in[2];
    const float* Weu  = (const float*)d_in[4];
    const float* beu  = (const float*)d_in[5];
    const float* lneg = (const float*)d_in[6];
    const float* lneb = (const float*)d_in[7];
    const float* Wf   = (const float*)d_in[8];
    const float* bfw  = (const float*)d_in[9];
    const float* Wb   = (const float*)d_in[10];
    const float* bbw  = (const float*)d_in[11];
    const float* lnhg = (const float*)d_in[12];
    const float* lnhb = (const float*)d_in[13];

    float* Hout = (float*)d_out;

    // workspace layout (bytes)
    char* ws = (char*)d_ws;
    unsigned short* msg    = (unsigned short*)(ws);                  // 256,000,000
    unsigned short* Ebuf   = (unsigned short*)(ws + 256000000);      // 128,000,000
    unsigned short* Hb     = (unsigned short*)(ws + 384000000);      //  25,600,000
    unsigned short* Weu_sw = (unsigned short*)(ws + 409600000);      //     196,608
    unsigned short* Wf_sw  = (unsigned short*)(ws + 409796608);      //     131,072
    unsigned short* Wb_sw  = (unsigned short*)(ws + 409927680);      //     131,072
    int*            cnt    = (int*)(ws + 410058752);                 //     400,000
    int*            partial= (int*)(ws + 410458752);                 //     400,000
    int*            bsum   = (int*)(ws + 410858752);                 //       2,048
    int*            off    = (int*)(ws + 410860800);                 //     400,016
    int*            pos    = (int*)(ws + 411260816);                 //     400,000
    int*            slotF  = (int*)(ws + 411660816);                 //   2,000,000
    int*            slotB  = (int*)(ws + 413660816);                 //   2,000,000

    wconv_kernel<<<(2*384*128 + 255)/256, 256, 0, stream>>>(Weu, Weu_sw, 384, 2*384*128);
    wconv_kernel<<<(2*256*128 + 255)/256, 256, 0, stream>>>(Wf,  Wf_sw,  256, 2*256*128);
    wconv_kernel<<<(2*256*128 + 255)/256, 256, 0, stream>>>(Wb,  Wb_sw,  256, 2*256*128);
    h2b_kernel<<<(N_NODES * D / 8 + 255)/256, 256, 0, stream>>>(H0, Hb, N_NODES * D / 8);

    // ---- CSR build ----
    const int nscan = (N_NODES + 255) / 256;   // 391
    hipMemsetAsync(cnt, 0, (size_t)N_NODES * sizeof(int), stream);
    count_kernel<<<(M_EDGES + 255) / 256, 256, 0, stream>>>(ht, cnt, M_EDGES);
    scanA_kernel<<<nscan, 256, 0, stream>>>(cnt, partial, bsum, N_NODES);
    scanB_kernel<<<1, 512, 0, stream>>>(bsum, nscan);
    scanC_kernel<<<nscan, 256, 0, stream>>>(partial, bsum, off, pos, N_NODES);
    fill_kernel<<<(M_EDGES + 255) / 256, 256, 0, stream>>>(ht, pos, slotF, slotB, M_EDGES);

    const int eblocks = (M_EDGES + 63) / 64;   // 7813

    for (int l = 0; l < 2; ++l) {
        const float* Hin = (l == 0) ? H0 : Hout;

        if (l == 0) {
            edge_mfma_kernel<true, true><<<eblocks, 64, 0, stream>>>(
                Hb, E0, nullptr, Ebuf, ht,
                Weu_sw, Wf_sw, Wb_sw,
                beu, lneg, lneb, bfw, bbw, slotF, slotB, msg);
        } else {
            edge_mfma_kernel<false, false><<<eblocks, 64, 0, stream>>>(
                Hb, nullptr, Ebuf, nullptr, ht,
                Weu_sw + 49152, Wf_sw + 32768, Wb_sw + 32768,
                beu + D, lneg + D, lneb + D, bfw + D, bbw + D, slotF, slotB, msg);
        }

        node_kernel<<<(N_NODES + 3) / 4, 256, 0, stream>>>(
            Hin, msg, off, lnhg + (size_t)l * D, lnhb + (size_t)l * D, Hout, Hb, N_NODES);
    }
}